// Round 1
// baseline (158.308 us; speedup 1.0000x reference)
//
#include <hip/hip_runtime.h>

// Receptive-field spike encoder:
//   out[t, b, d] = ( clip( (int)(scaling[d] * |x[b] - center[d]|), 0, T-1 ) == t ) ? 1 : 0
// Output [T, B, N] float32. Memory-bound: 512 MiB of coalesced stores.
// One thread per (t, b); each thread produces all N=16 outputs (64 B) as 4x float4.

__global__ void rf_encode_kernel(const float* __restrict__ x,
                                 const float* __restrict__ center,
                                 const float* __restrict__ scaling,
                                 float* __restrict__ out,
                                 int B, int N, int T) {
    long long tid = (long long)blockIdx.x * blockDim.x + threadIdx.x;
    long long total = (long long)T * B;
    if (tid >= total) return;

    int b = (int)(tid % B);
    int t = (int)(tid / B);

    float xb = x[b];
    float* o = out + ((long long)t * B + (long long)b) * N;

    if (N == 16) {
        // fast path: 4x float4 stores, 64 contiguous bytes per thread
        #pragma unroll
        for (int j = 0; j < 4; ++j) {
            float r[4];
            #pragma unroll
            for (int k = 0; k < 4; ++k) {
                int d = j * 4 + k;
                // exact numpy op sequence: sub, abs, mul, trunc-to-int32
                float dist = fabsf(xb - center[d]);
                int ts = (int)(scaling[d] * dist);
                ts = min(max(ts, 0), T - 1);
                r[k] = (ts == t) ? 1.0f : 0.0f;
            }
            reinterpret_cast<float4*>(o)[j] = make_float4(r[0], r[1], r[2], r[3]);
        }
    } else {
        for (int d = 0; d < N; ++d) {
            float dist = fabsf(xb - center[d]);
            int ts = (int)(scaling[d] * dist);
            ts = min(max(ts, 0), T - 1);
            o[d] = (ts == t) ? 1.0f : 0.0f;
        }
    }
}

extern "C" void kernel_launch(void* const* d_in, const int* in_sizes, int n_in,
                              void* d_out, int out_size, void* d_ws, size_t ws_size,
                              hipStream_t stream) {
    const float* x       = (const float*)d_in[0];
    const float* center  = (const float*)d_in[1];
    const float* scaling = (const float*)d_in[2];
    float* out = (float*)d_out;

    int B = in_sizes[0];
    int N = in_sizes[1];
    // time_steps comes as a device scalar; recover T from the output size instead.
    int T = (int)((long long)out_size / ((long long)B * (long long)N));

    long long total = (long long)T * B;
    const int block = 256;
    int blocks = (int)((total + block - 1) / block);

    rf_encode_kernel<<<blocks, block, 0, stream>>>(x, center, scaling, out, B, N, T);
}

// Round 2
// 156.146 us; speedup vs baseline: 1.0138x; 1.0138x over previous
//
#include <hip/hip_runtime.h>

// Receptive-field spike encoder:
//   out[t, b, d] = ( clip( (int)(scaling[d] * |x[b] - center[d]|), 0, T-1 ) == t ) ? 1 : 0
// Output [T, B, N=16] float32, 512 MiB -> purely write-BW-bound.
//
// Round-2 structure: t-blocking. One thread per (b, t-group of TB=8 planes).
// t_spike[d] is t-independent, so compute the 16 spike times ONCE per thread,
// then emit TB * 64 B of one-hot rows with only a cmp+select per (t,d).
// VALU per byte drops ~4.5x below the HBM-write requirement.

#define TBLK 8  // t-planes per thread

__global__ void rf_encode_kernel(const float* __restrict__ x,
                                 const float* __restrict__ center,
                                 const float* __restrict__ scaling,
                                 float* __restrict__ out,
                                 int B, int T) {
    int b = blockIdx.x * blockDim.x + threadIdx.x;
    if (b >= B) return;
    int t0 = blockIdx.y * TBLK;

    float xb = x[b];

    // spike time per receptive field (t-independent) — computed once
    int ts[16];
    #pragma unroll
    for (int d = 0; d < 16; ++d) {
        // exact numpy op sequence: sub, abs, mul, trunc-to-int32, clip
        float dist = fabsf(xb - center[d]);
        int v = (int)(scaling[d] * dist);
        ts[d] = min(max(v, 0), T - 1);
    }

    #pragma unroll
    for (int i = 0; i < TBLK; ++i) {
        int t = t0 + i;
        if (t >= T) break;
        float r[16];
        #pragma unroll
        for (int d = 0; d < 16; ++d) {
            r[d] = (ts[d] == t) ? 1.0f : 0.0f;
        }
        float* o = out + ((long long)t * B + (long long)b) * 16;
        float4* o4 = reinterpret_cast<float4*>(o);
        o4[0] = make_float4(r[0],  r[1],  r[2],  r[3]);
        o4[1] = make_float4(r[4],  r[5],  r[6],  r[7]);
        o4[2] = make_float4(r[8],  r[9],  r[10], r[11]);
        o4[3] = make_float4(r[12], r[13], r[14], r[15]);
    }
}

// generic fallback for N != 16 (not expected in this problem)
__global__ void rf_encode_generic(const float* __restrict__ x,
                                  const float* __restrict__ center,
                                  const float* __restrict__ scaling,
                                  float* __restrict__ out,
                                  int B, int N, int T) {
    long long tid = (long long)blockIdx.x * blockDim.x + threadIdx.x;
    long long total = (long long)T * B;
    if (tid >= total) return;
    int b = (int)(tid % B);
    int t = (int)(tid / B);
    float xb = x[b];
    float* o = out + ((long long)t * B + (long long)b) * N;
    for (int d = 0; d < N; ++d) {
        float dist = fabsf(xb - center[d]);
        int v = (int)(scaling[d] * dist);
        v = min(max(v, 0), T - 1);
        o[d] = (v == t) ? 1.0f : 0.0f;
    }
}

extern "C" void kernel_launch(void* const* d_in, const int* in_sizes, int n_in,
                              void* d_out, int out_size, void* d_ws, size_t ws_size,
                              hipStream_t stream) {
    const float* x       = (const float*)d_in[0];
    const float* center  = (const float*)d_in[1];
    const float* scaling = (const float*)d_in[2];
    float* out = (float*)d_out;

    int B = in_sizes[0];
    int N = in_sizes[1];
    int T = (int)((long long)out_size / ((long long)B * (long long)N));

    if (N == 16) {
        const int block = 256;
        dim3 grid((B + block - 1) / block, (T + TBLK - 1) / TBLK);
        rf_encode_kernel<<<grid, block, 0, stream>>>(x, center, scaling, out, B, T);
    } else {
        long long total = (long long)T * B;
        const int block = 256;
        int blocks = (int)((total + block - 1) / block);
        rf_encode_generic<<<blocks, block, 0, stream>>>(x, center, scaling, out, B, N, T);
    }
}

// Round 3
// 125.951 us; speedup vs baseline: 1.2569x; 1.2397x over previous
//
#include <hip/hip_runtime.h>

// Receptive-field spike encoder:
//   out[t, b, d] = ( clip( (int)(scaling[d] * |x[b] - center[d]|), 0, T-1 ) == t ) ? 1 : 0
// Output [T, B, N=16] float32, 512 MiB -> write-BW-bound.
//
// Round-3: fix store coalescing. Previous kernels had each thread own a 64B
// row, so ONE store instruction touched 64 different cache lines (16B each) —
// 16x request amplification at the CU->L2 interface, capping at ~3.4 TB/s.
// Now: one thread per quarter-row (b, d-quarter). Lane i stores 16B at
// base + i*16 -> each wave store instruction covers a contiguous 1 KiB.

#define TBLK 16  // t-planes per thread

__global__ void rf_encode_q(const float* __restrict__ x,
                            const float* __restrict__ center,
                            const float* __restrict__ scaling,
                            float* __restrict__ out,
                            int B, int T) {
    int q = blockIdx.x * blockDim.x + threadIdx.x;   // [0, B*4)
    if (q >= B * 4) return;
    int b  = q >> 2;
    int d0 = (q & 3) * 4;

    float xb = x[b];

    // spike times for this thread's 4 receptive fields (t-independent)
    int ts[4];
    #pragma unroll
    for (int k = 0; k < 4; ++k) {
        // exact numpy op sequence: sub, abs, mul, trunc-to-int32, clip
        float dist = fabsf(xb - center[d0 + k]);
        int v = (int)(scaling[d0 + k] * dist);
        ts[k] = min(max(v, 0), T - 1);
    }

    int t0 = blockIdx.y * TBLK;
    // flat float offset of (t0, b, d0); advances by B*16 floats per t-plane
    float* o = out + ((long long)t0 * B + (long long)b) * 16 + d0;
    const long long tstride = (long long)B * 16;

    #pragma unroll
    for (int i = 0; i < TBLK; ++i) {
        int t = t0 + i;
        if (t >= T) break;
        float4 r = make_float4(ts[0] == t ? 1.0f : 0.0f,
                               ts[1] == t ? 1.0f : 0.0f,
                               ts[2] == t ? 1.0f : 0.0f,
                               ts[3] == t ? 1.0f : 0.0f);
        *reinterpret_cast<float4*>(o) = r;
        o += tstride;
    }
}

// generic fallback for N not handled by the fast path (not expected here)
__global__ void rf_encode_generic(const float* __restrict__ x,
                                  const float* __restrict__ center,
                                  const float* __restrict__ scaling,
                                  float* __restrict__ out,
                                  int B, int N, int T) {
    long long tid = (long long)blockIdx.x * blockDim.x + threadIdx.x;
    long long total = (long long)T * B;
    if (tid >= total) return;
    int b = (int)(tid % B);
    int t = (int)(tid / B);
    float xb = x[b];
    float* o = out + ((long long)t * B + (long long)b) * N;
    for (int d = 0; d < N; ++d) {
        float dist = fabsf(xb - center[d]);
        int v = (int)(scaling[d] * dist);
        v = min(max(v, 0), T - 1);
        o[d] = (v == t) ? 1.0f : 0.0f;
    }
}

extern "C" void kernel_launch(void* const* d_in, const int* in_sizes, int n_in,
                              void* d_out, int out_size, void* d_ws, size_t ws_size,
                              hipStream_t stream) {
    const float* x       = (const float*)d_in[0];
    const float* center  = (const float*)d_in[1];
    const float* scaling = (const float*)d_in[2];
    float* out = (float*)d_out;

    int B = in_sizes[0];
    int N = in_sizes[1];
    int T = (int)((long long)out_size / ((long long)B * (long long)N));

    if (N == 16) {
        const int block = 256;
        dim3 grid((B * 4 + block - 1) / block, (T + TBLK - 1) / TBLK);
        rf_encode_q<<<grid, block, 0, stream>>>(x, center, scaling, out, B, T);
    } else {
        long long total = (long long)T * B;
        const int block = 256;
        int blocks = (int)((total + block - 1) / block);
        rf_encode_generic<<<blocks, block, 0, stream>>>(x, center, scaling, out, B, N, T);
    }
}